// Round 1
// baseline (290.396 us; speedup 1.0000x reference)
//
#include <hip/hip_runtime.h>
#include <math.h>

#define B_ 16
#define D_ 1024
#define T_ 4096
#define CS_ 1024
#define CD_ 8

// ---------- numpy-mimicking fp32 helpers ----------
__device__ __forceinline__ float f_tree8(const float r[8]) {
  // numpy pairwise combine of 8 accumulators:
  // ((r0+r1)+(r2+r3)) + ((r4+r5)+(r6+r7))
  return __fadd_rn(
      __fadd_rn(__fadd_rn(r[0], r[1]), __fadd_rn(r[2], r[3])),
      __fadd_rn(__fadd_rn(r[4], r[5]), __fadd_rn(r[6], r[7])));
}
__device__ __forceinline__ float f_sumsq8(const float x[8]) {
  float s[8];
#pragma unroll
  for (int k = 0; k < 8; ++k) s[k] = __fmul_rn(x[k], x[k]);
  return f_tree8(s);
}

// ---------- setup: normalize W_in, W_out, codebook ----------
// ws layout:
//   WTd  : double[1024][8]  (W_in^T as f64 copies of fp32-rounded W_in)
//   cbn  : float [1024][8]  (l2-normalized codebook)
//   scb  : float [1024]     (sum(cbn^2) per row, numpy tree8)
//   woutn: float [1024][8]  (weight-normed W_out rows)
//   lossp: float [512]      (per-block loss partials)
__global__ __launch_bounds__(1024) void vq_setup(
    const float* __restrict__ cb, const float* __restrict__ g_in,
    const float* __restrict__ v_in, const float* __restrict__ g_out,
    const float* __restrict__ v_out, double* __restrict__ WTd,
    float* __restrict__ cbn, float* __restrict__ scb,
    float* __restrict__ woutn) {
  __shared__ float sv[8 * 1024];
  __shared__ float leafs[64];
  __shared__ float den[8];
  const int tid = threadIdx.x;

  for (int i = tid; i < 8 * 1024; i += 1024) sv[i] = v_in[i];
  __syncthreads();

  // numpy pairwise_sum(1024) = 8 leaf blocks of 128 (8-accumulator pattern),
  // combined with the same binary tree as tree8.
  if (tid < 64) {
    const int c = tid >> 3, l = tid & 7;
    const float* a = sv + c * 1024 + l * 128;
    float r[8];
#pragma unroll
    for (int k = 0; k < 8; ++k) r[k] = __fmul_rn(a[k], a[k]);
    for (int i = 8; i < 128; i += 8) {
#pragma unroll
      for (int k = 0; k < 8; ++k)
        r[k] = __fadd_rn(r[k], __fmul_rn(a[i + k], a[i + k]));
    }
    leafs[c * 8 + l] = f_tree8(r);
  }
  __syncthreads();
  if (tid < 8) {
    const float* L = leafs + tid * 8;
    float lr[8];
#pragma unroll
    for (int k = 0; k < 8; ++k) lr[k] = L[k];
    const float s = f_tree8(lr);
    den[tid] = fmaxf(__fsqrt_rn(s), 1e-12f);
  }
  __syncthreads();

  if (tid < 1024) {
    // W_in^T (store fp32-rounded values widened to f64)
#pragma unroll
    for (int c = 0; c < 8; ++c) {
      const float w = __fdiv_rn(__fmul_rn(g_in[c], sv[c * 1024 + tid]), den[c]);
      WTd[tid * 8 + c] = (double)w;
    }
    // codebook normalize
    {
      const float* cr = cb + tid * 8;
      float q[8];
#pragma unroll
      for (int c = 0; c < 8; ++c) q[c] = cr[c];
      const float nn = f_sumsq8(q);
      const float dd = fmaxf(__fsqrt_rn(nn), 1e-12f);
      float qn[8];
#pragma unroll
      for (int c = 0; c < 8; ++c) {
        qn[c] = __fdiv_rn(q[c], dd);
        cbn[tid * 8 + c] = qn[c];
      }
      scb[tid] = f_sumsq8(qn);
    }
    // W_out weight-norm (rows of 8)
    {
      const float* vr = v_out + tid * 8;
      float w[8];
#pragma unroll
      for (int c = 0; c < 8; ++c) w[c] = vr[c];
      const float n2 = f_sumsq8(w);
      const float d2 = fmaxf(__fsqrt_rn(n2), 1e-12f);
      const float go = g_out[tid];
#pragma unroll
      for (int c = 0; c < 8; ++c)
        woutn[tid * 8 + c] = __fdiv_rn(__fmul_rn(go, w[c]), d2);
    }
  }
}

// ---------- main: thread-per-t; z_e (f64) -> argmin -> loss -> out ----------
__global__ __launch_bounds__(128) void vq_main(
    const float* __restrict__ z, const float* __restrict__ cbraw,
    const float* __restrict__ b_in, const float* __restrict__ b_out,
    const double* __restrict__ WTd, const float* __restrict__ cbn,
    const float* __restrict__ scb, const float* __restrict__ woutn,
    float* __restrict__ out, float* __restrict__ oidx,
    float* __restrict__ lossp) {
  extern __shared__ char smem[];  // 65536 bytes, reused per phase
  const int tid = threadIdx.x;
  const int blk = blockIdx.x;        // 512 = 16 b * 32 tiles
  const int b = blk >> 5;
  const int tile = blk & 31;
  const int t = tile * 128 + tid;

  // ---- phase 1: z_e[c] = sum_d z[b,d,t] * W_in[c,d]  (f64 accumulate) ----
  {
    double* Wl = (double*)smem;  // 8192 doubles = 64 KB
    for (int i = tid; i < 8192; i += 128) Wl[i] = WTd[i];
    __syncthreads();

    const float* zp = z + (size_t)b * D_ * (size_t)T_ + t;
    double acc[8];
#pragma unroll
    for (int c = 0; c < 8; ++c) acc[c] = 0.0;

#pragma unroll 16
    for (int d = 0; d < D_; ++d) {
      const double zd = (double)zp[(size_t)d * T_];
      const double2* w2 = (const double2*)(Wl + d * 8);
#pragma unroll
      for (int p = 0; p < 4; ++p) {
        const double2 wv = w2[p];
        acc[2 * p] = fma(zd, wv.x, acc[2 * p]);
        acc[2 * p + 1] = fma(zd, wv.y, acc[2 * p + 1]);
      }
    }
    __syncthreads();  // done with Wl

    // materialize fp32 z_e (+ b_in), normalize (numpy-mimicked)
    float e[8], en[8];
#pragma unroll
    for (int c = 0; c < 8; ++c) e[c] = __fadd_rn((float)acc[c], b_in[c]);
    const float n2 = f_sumsq8(e);
    const float dn = fmaxf(__fsqrt_rn(n2), 1e-12f);
#pragma unroll
    for (int c = 0; c < 8; ++c) en[c] = __fdiv_rn(e[c], dn);
    const float s_enc = f_sumsq8(en);

    // ---- phase 2: nearest code (first-min, exact ref op order) ----
    float* cbl = (float*)smem;       // 8192 floats
    float* scbl = cbl + 8192;        // 1024 floats
    for (int i = tid; i < 8192; i += 128) cbl[i] = cbn[i];
    for (int i = tid; i < 1024; i += 128) scbl[i] = scb[i];
    __syncthreads();

    float best = INFINITY;
    int bj = 0;
#pragma unroll 4
    for (int j = 0; j < CS_; ++j) {
      const float4* cr4 = (const float4*)(cbl + j * 8);
      const float4 lo = cr4[0], hi = cr4[1];
      float dot = 0.f;
      dot = fmaf(en[0], lo.x, dot);
      dot = fmaf(en[1], lo.y, dot);
      dot = fmaf(en[2], lo.z, dot);
      dot = fmaf(en[3], lo.w, dot);
      dot = fmaf(en[4], hi.x, dot);
      dot = fmaf(en[5], hi.y, dot);
      dot = fmaf(en[6], hi.z, dot);
      dot = fmaf(en[7], hi.w, dot);
      const float dist =
          __fadd_rn(__fsub_rn(s_enc, __fmul_rn(2.0f, dot)), scbl[j]);
      if (dist < best) { best = dist; bj = j; }
    }
    oidx[(size_t)b * T_ + t] = (float)bj;

    // ---- loss partial: sum_c (z_e - codebook[bj])^2 ----
    float q[8];
    const float* cq = cbraw + (size_t)bj * 8;
#pragma unroll
    for (int c = 0; c < 8; ++c) q[c] = cq[c];
    float lsum = 0.f;
#pragma unroll
    for (int c = 0; c < 8; ++c) {
      const float df = __fsub_rn(e[c], q[c]);
      lsum = fmaf(df, df, lsum);
    }
    __syncthreads();  // done with cbl/scbl
    {
      float* red = (float*)smem;
      red[tid] = lsum;
      __syncthreads();
      for (int s = 64; s > 0; s >>= 1) {
        if (tid < s) red[tid] += red[tid + s];
        __syncthreads();
      }
      if (tid == 0) lossp[blk] = red[0];
    }
    __syncthreads();

    // ---- phase 3: out[b,d,t] = dot8(codebook[bj], W_out_n[d]) + b_out[d] ----
    float* wol = (float*)smem;    // 8192 floats
    float* bol = wol + 8192;      // 1024 floats
    for (int i = tid; i < 8192; i += 128) wol[i] = woutn[i];
    for (int i = tid; i < 1024; i += 128) bol[i] = b_out[i];
    __syncthreads();

    float* op = out + (size_t)b * D_ * (size_t)T_ + t;
#pragma unroll 8
    for (int d = 0; d < D_; ++d) {
      const float4* wr4 = (const float4*)(wol + d * 8);
      const float4 lo = wr4[0], hi = wr4[1];
      float dot = 0.f;
      dot = fmaf(q[0], lo.x, dot);
      dot = fmaf(q[1], lo.y, dot);
      dot = fmaf(q[2], lo.z, dot);
      dot = fmaf(q[3], lo.w, dot);
      dot = fmaf(q[4], hi.x, dot);
      dot = fmaf(q[5], hi.y, dot);
      dot = fmaf(q[6], hi.z, dot);
      dot = fmaf(q[7], hi.w, dot);
      op[(size_t)d * T_] = __fadd_rn(dot, bol[d]);
    }
  }
}

// ---------- finalize loss: per-b deterministic sum of 32 partials ----------
__global__ __launch_bounds__(64) void vq_fin(const float* __restrict__ lossp,
                                             float* __restrict__ oloss) {
  const int tid = threadIdx.x;
  if (tid < B_) {
    float s = 0.f;
    for (int i = 0; i < 32; ++i) s += lossp[tid * 32 + i];
    oloss[tid] = s * (1.25f / 32768.0f);
  }
}

extern "C" void kernel_launch(void* const* d_in, const int* in_sizes, int n_in,
                              void* d_out, int out_size, void* d_ws,
                              size_t ws_size, hipStream_t stream) {
  (void)in_sizes; (void)n_in; (void)out_size; (void)ws_size;
  const float* z = (const float*)d_in[0];
  const float* cb = (const float*)d_in[1];
  const float* g_in = (const float*)d_in[2];
  const float* v_in = (const float*)d_in[3];
  const float* b_in = (const float*)d_in[4];
  const float* g_out = (const float*)d_in[5];
  const float* v_out = (const float*)d_in[6];
  const float* b_out = (const float*)d_in[7];
  float* out = (float*)d_out;

  char* ws = (char*)d_ws;
  double* WTd = (double*)ws;                  // 65536 B
  float* cbn = (float*)(ws + 65536);          // 32768 B
  float* scb = (float*)(ws + 98304);          // 4096 B
  float* woutn = (float*)(ws + 102400);       // 32768 B
  float* lossp = (float*)(ws + 135168);       // 2048 B

  float* oidx = out + (size_t)B_ * D_ * T_;
  float* oloss = oidx + (size_t)B_ * T_;

  vq_setup<<<1, 1024, 0, stream>>>(cb, g_in, v_in, g_out, v_out, WTd, cbn, scb,
                                   woutn);
  vq_main<<<512, 128, 65536, stream>>>(z, cb, b_in, b_out, WTd, cbn, scb,
                                       woutn, out, oidx, lossp);
  vq_fin<<<1, 64, 0, stream>>>(lossp, oloss);
}

// Round 2
// 215.795 us; speedup vs baseline: 1.3457x; 1.3457x over previous
//
#include <hip/hip_runtime.h>
#include <math.h>

#define B_ 16
#define D_ 1024
#define T_ 4096
#define CS_ 1024
#define CD_ 8

// ---------- numpy-mimicking fp32 helpers ----------
__device__ __forceinline__ float f_tree8(const float r[8]) {
  return __fadd_rn(
      __fadd_rn(__fadd_rn(r[0], r[1]), __fadd_rn(r[2], r[3])),
      __fadd_rn(__fadd_rn(r[4], r[5]), __fadd_rn(r[6], r[7])));
}
__device__ __forceinline__ float f_sumsq8(const float x[8]) {
  float s[8];
#pragma unroll
  for (int k = 0; k < 8; ++k) s[k] = __fmul_rn(x[k], x[k]);
  return f_tree8(s);
}

// ---------- setup: normalize W_in, W_out, codebook ----------
// ws layout:
//   WTf  : float [1024][8]  (W_in^T, fp32)            @ 0      (32768 B)
//   cbn  : float [1024][8]  (l2-normalized codebook)  @ 32768  (32768 B)
//   scb  : float [1024]     (sum(cbn^2), numpy tree8) @ 65536  (4096 B)
//   woutn: float [1024][8]  (weight-normed W_out)     @ 69632  (32768 B)
//   lossp: float [1024]     (per-block loss partials) @ 102400 (4096 B)
__global__ __launch_bounds__(1024) void vq_setup(
    const float* __restrict__ cb, const float* __restrict__ g_in,
    const float* __restrict__ v_in, const float* __restrict__ g_out,
    const float* __restrict__ v_out, float* __restrict__ WTf,
    float* __restrict__ cbn, float* __restrict__ scb,
    float* __restrict__ woutn) {
  __shared__ float sv[8 * 1024];
  __shared__ float leafs[64];
  __shared__ float den[8];
  const int tid = threadIdx.x;

  for (int i = tid; i < 8 * 1024; i += 1024) sv[i] = v_in[i];
  __syncthreads();

  // numpy pairwise_sum(1024): 8 leaf blocks of 128 (8-accumulator pattern),
  // combined with the same binary tree as tree8.
  if (tid < 64) {
    const int c = tid >> 3, l = tid & 7;
    const float* a = sv + c * 1024 + l * 128;
    float r[8];
#pragma unroll
    for (int k = 0; k < 8; ++k) r[k] = __fmul_rn(a[k], a[k]);
    for (int i = 8; i < 128; i += 8) {
#pragma unroll
      for (int k = 0; k < 8; ++k)
        r[k] = __fadd_rn(r[k], __fmul_rn(a[i + k], a[i + k]));
    }
    leafs[c * 8 + l] = f_tree8(r);
  }
  __syncthreads();
  if (tid < 8) {
    const float* L = leafs + tid * 8;
    float lr[8];
#pragma unroll
    for (int k = 0; k < 8; ++k) lr[k] = L[k];
    const float s = f_tree8(lr);
    den[tid] = fmaxf(__fsqrt_rn(s), 1e-12f);
  }
  __syncthreads();

  if (tid < 1024) {
#pragma unroll
    for (int c = 0; c < 8; ++c) {
      const float w = __fdiv_rn(__fmul_rn(g_in[c], sv[c * 1024 + tid]), den[c]);
      WTf[tid * 8 + c] = w;
    }
    {
      const float* cr = cb + tid * 8;
      float q[8];
#pragma unroll
      for (int c = 0; c < 8; ++c) q[c] = cr[c];
      const float nn = f_sumsq8(q);
      const float dd = fmaxf(__fsqrt_rn(nn), 1e-12f);
      float qn[8];
#pragma unroll
      for (int c = 0; c < 8; ++c) {
        qn[c] = __fdiv_rn(q[c], dd);
        cbn[tid * 8 + c] = qn[c];
      }
      scb[tid] = f_sumsq8(qn);
    }
    {
      const float* vr = v_out + tid * 8;
      float w[8];
#pragma unroll
      for (int c = 0; c < 8; ++c) w[c] = vr[c];
      const float n2 = f_sumsq8(w);
      const float d2 = fmaxf(__fsqrt_rn(n2), 1e-12f);
      const float go = g_out[tid];
#pragma unroll
      for (int c = 0; c < 8; ++c)
        woutn[tid * 8 + c] = __fdiv_rn(__fmul_rn(go, w[c]), d2);
    }
  }
}

// ---------- main kernel ----------
// Grid: 1024 blocks x 256 threads. Block owns 64 consecutive t of one b.
// Thread = (qt, tl): qt = tid>>6 (quarter-wave = one full wave), tl = tid&63.
// Phase 1: quarter qt accumulates d in [qt*256, qt*256+256) in f64.
// Combine 4 partials per t via transposed LDS f64 buffer.
// Phase 2: quarter qt scans codes [qt*256, ...+256); strict-< combine keeps
//          first-min semantics.
// Phase 3: quarter qt writes d in [qt*256, ...+256).
__global__ __launch_bounds__(256, 4) void vq_main(
    const float* __restrict__ z, const float* __restrict__ cbraw,
    const float* __restrict__ b_in, const float* __restrict__ b_out,
    const float* __restrict__ WTf, const float* __restrict__ cbn,
    const float* __restrict__ scb, const float* __restrict__ woutn,
    float* __restrict__ out, float* __restrict__ oidx,
    float* __restrict__ lossp) {
  extern __shared__ char smem[];  // 36864 bytes, reused per phase
  const int tid = threadIdx.x;
  const int qt = tid >> 6;
  const int tl = tid & 63;
  const int blk = blockIdx.x;  // 1024 = 16 b * 64 tiles
  const int b = blk >> 6;
  const int tile = blk & 63;
  const int t = tile * 64 + tl;

  // ---- phase 1: partial z_e in f64 over this quarter's d-range ----
  float* Wl = (float*)smem;  // 8192 f32 = 32 KB
  for (int i = tid; i < 8192; i += 256) Wl[i] = WTf[i];
  __syncthreads();

  const float* zp = z + ((size_t)b * D_ + (size_t)qt * 256) * T_ + t;
  double acc[8];
#pragma unroll
  for (int c = 0; c < 8; ++c) acc[c] = 0.0;

  const float4* wbase = (const float4*)(Wl + qt * 256 * 8);
#pragma unroll 8
  for (int d = 0; d < 256; ++d) {
    const double zd = (double)zp[(size_t)d * T_];
    const float4 lo = wbase[2 * d];
    const float4 hi = wbase[2 * d + 1];
    acc[0] = fma(zd, (double)lo.x, acc[0]);
    acc[1] = fma(zd, (double)lo.y, acc[1]);
    acc[2] = fma(zd, (double)lo.z, acc[2]);
    acc[3] = fma(zd, (double)lo.w, acc[3]);
    acc[4] = fma(zd, (double)hi.x, acc[4]);
    acc[5] = fma(zd, (double)hi.y, acc[5]);
    acc[6] = fma(zd, (double)hi.z, acc[6]);
    acc[7] = fma(zd, (double)hi.w, acc[7]);
  }
  __syncthreads();  // Wl dead

  // transposed accbuf: accb[c][tid], stride-8B across lanes (2-way, free)
  double* accb = (double*)smem;  // 2048 f64 = 16 KB
#pragma unroll
  for (int c = 0; c < 8; ++c) accb[c * 256 + tid] = acc[c];
  __syncthreads();

  double tot[8];
#pragma unroll
  for (int c = 0; c < 8; ++c) {
    const double* row = accb + c * 256 + tl;
    tot[c] = ((row[0] + row[64]) + row[128]) + row[192];
  }
  __syncthreads();  // accb dead

  // materialize fp32 z_e (+ b_in), normalize (numpy-mimicked)
  float e[8], en[8];
#pragma unroll
  for (int c = 0; c < 8; ++c) e[c] = __fadd_rn((float)tot[c], b_in[c]);
  const float n2 = f_sumsq8(e);
  const float dn = fmaxf(__fsqrt_rn(n2), 1e-12f);
#pragma unroll
  for (int c = 0; c < 8; ++c) en[c] = __fdiv_rn(e[c], dn);
  const float s_enc = f_sumsq8(en);

  // ---- phase 2: nearest code, 4-way split scan ----
  float* cbl = (float*)smem;        // 8192 f32
  float* scbl = cbl + 8192;         // 1024 f32
  for (int i = tid; i < 8192; i += 256) cbl[i] = cbn[i];
  for (int i = tid; i < 1024; i += 256) scbl[i] = scb[i];
  __syncthreads();

  float best = INFINITY;
  int bj = qt * 256;
  {
    const int j0 = qt * 256;
#pragma unroll 4
    for (int jj = 0; jj < 256; ++jj) {
      const int j = j0 + jj;
      const float4* cr4 = (const float4*)(cbl + j * 8);
      const float4 lo = cr4[0], hi = cr4[1];
      float dot = 0.f;
      dot = fmaf(en[0], lo.x, dot);
      dot = fmaf(en[1], lo.y, dot);
      dot = fmaf(en[2], lo.z, dot);
      dot = fmaf(en[3], lo.w, dot);
      dot = fmaf(en[4], hi.x, dot);
      dot = fmaf(en[5], hi.y, dot);
      dot = fmaf(en[6], hi.z, dot);
      dot = fmaf(en[7], hi.w, dot);
      const float dist =
          __fadd_rn(__fsub_rn(s_enc, __fmul_rn(2.0f, dot)), scbl[j]);
      if (dist < best) { best = dist; bj = j; }
    }
  }
  __syncthreads();  // cbl/scbl dead

  // candidate combine (SoA: conflict-free stride-4B)
  float* distf = (float*)smem;          // 256 f32
  int* candj = (int*)(smem + 1024);     // 256 i32
  distf[tid] = best;
  candj[tid] = bj;
  __syncthreads();

  float bd = distf[tl];
  int bi = candj[tl];
#pragma unroll
  for (int qq = 1; qq < 4; ++qq) {
    const float dd = distf[qq * 64 + tl];
    const int jj = candj[qq * 64 + tl];
    if (dd < bd) { bd = dd; bi = jj; }  // strict <: lower quarter wins ties
  }
  __syncthreads();  // cand buffers dead

  if (tid < 64) oidx[(size_t)b * T_ + t] = (float)bi;

  // ---- loss partial (wave 0 only; all quarters hold identical e, cq) ----
  float cq[8];
  {
    const float* cp = cbraw + (size_t)bi * 8;
#pragma unroll
    for (int c = 0; c < 8; ++c) cq[c] = cp[c];
  }
  if (tid < 64) {
    float lsum = 0.f;
#pragma unroll
    for (int c = 0; c < 8; ++c) {
      const float df = __fsub_rn(e[c], cq[c]);
      lsum = fmaf(df, df, lsum);
    }
#pragma unroll
    for (int off = 32; off > 0; off >>= 1)
      lsum += __shfl_down(lsum, off, 64);
    if (tl == 0) lossp[blk] = lsum;
  }

  // ---- phase 3: out[b,d,t] = dot8(codebook[bi], W_out_n[d]) + b_out[d] ----
  float* wol = (float*)smem;            // 8192 f32
  float* bol = (float*)(smem + 32768);  // 1024 f32
  for (int i = tid; i < 8192; i += 256) wol[i] = woutn[i];
  for (int i = tid; i < 1024; i += 256) bol[i] = b_out[i];
  __syncthreads();

  float* op = out + ((size_t)b * D_ + (size_t)qt * 256) * T_ + t;
  const float4* wob = (const float4*)(wol + qt * 256 * 8);
  const float* bob = bol + qt * 256;
#pragma unroll 8
  for (int d = 0; d < 256; ++d) {
    const float4 lo = wob[2 * d];
    const float4 hi = wob[2 * d + 1];
    float dot = 0.f;
    dot = fmaf(cq[0], lo.x, dot);
    dot = fmaf(cq[1], lo.y, dot);
    dot = fmaf(cq[2], lo.z, dot);
    dot = fmaf(cq[3], lo.w, dot);
    dot = fmaf(cq[4], hi.x, dot);
    dot = fmaf(cq[5], hi.y, dot);
    dot = fmaf(cq[6], hi.z, dot);
    dot = fmaf(cq[7], hi.w, dot);
    op[(size_t)d * T_] = __fadd_rn(dot, bob[d]);
  }
}

// ---------- finalize loss ----------
__global__ __launch_bounds__(64) void vq_fin(const float* __restrict__ lossp,
                                             float* __restrict__ oloss) {
  const int tid = threadIdx.x;
  if (tid < B_) {
    float s = 0.f;
    for (int i = 0; i < 64; ++i) s += lossp[tid * 64 + i];
    oloss[tid] = s * (1.25f / 32768.0f);
  }
}

extern "C" void kernel_launch(void* const* d_in, const int* in_sizes, int n_in,
                              void* d_out, int out_size, void* d_ws,
                              size_t ws_size, hipStream_t stream) {
  (void)in_sizes; (void)n_in; (void)out_size; (void)ws_size;
  const float* z = (const float*)d_in[0];
  const float* cb = (const float*)d_in[1];
  const float* g_in = (const float*)d_in[2];
  const float* v_in = (const float*)d_in[3];
  const float* b_in = (const float*)d_in[4];
  const float* g_out = (const float*)d_in[5];
  const float* v_out = (const float*)d_in[6];
  const float* b_out = (const float*)d_in[7];
  float* out = (float*)d_out;

  char* ws = (char*)d_ws;
  float* WTf = (float*)ws;                // 32768 B
  float* cbn = (float*)(ws + 32768);      // 32768 B
  float* scb = (float*)(ws + 65536);      // 4096 B
  float* woutn = (float*)(ws + 69632);    // 32768 B
  float* lossp = (float*)(ws + 102400);   // 4096 B

  float* oidx = out + (size_t)B_ * D_ * T_;
  float* oloss = oidx + (size_t)B_ * T_;

  vq_setup<<<1, 1024, 0, stream>>>(cb, g_in, v_in, g_out, v_out, WTf, cbn, scb,
                                   woutn);
  vq_main<<<1024, 256, 36864, stream>>>(z, cb, b_in, b_out, WTf, cbn, scb,
                                        woutn, out, oidx, lossp);
  vq_fin<<<1, 64, 0, stream>>>(lossp, oloss);
}

// Round 3
// 188.194 us; speedup vs baseline: 1.5431x; 1.1467x over previous
//
#include <hip/hip_runtime.h>
#include <math.h>

#define B_ 16
#define D_ 1024
#define T_ 4096
#define CS_ 1024
#define CD_ 8

// ---------- numpy-mimicking fp32 helpers ----------
__device__ __forceinline__ float f_tree8(const float r[8]) {
  return __fadd_rn(
      __fadd_rn(__fadd_rn(r[0], r[1]), __fadd_rn(r[2], r[3])),
      __fadd_rn(__fadd_rn(r[4], r[5]), __fadd_rn(r[6], r[7])));
}
__device__ __forceinline__ float f_sumsq8(const float x[8]) {
  float s[8];
#pragma unroll
  for (int k = 0; k < 8; ++k) s[k] = __fmul_rn(x[k], x[k]);
  return f_tree8(s);
}

// ---------- setup: normalize W_in, W_out, codebook; pack tables ----------
// ws layout:
//   WTd  : double[1024][8]   (W_in^T, fp32-rounded widened to f64)  @ 0      (65536 B)
//   cb16 : float [1024][16]  ({cbn[8], scb, pad})                   @ 65536  (65536 B)
//   wo16 : float [1024][16]  ({woutn[8], b_out, pad})               @ 131072 (65536 B)
//   lossp: float [1024]                                             @ 196608 (4096 B)
__global__ __launch_bounds__(1024) void vq_setup(
    const float* __restrict__ cb, const float* __restrict__ g_in,
    const float* __restrict__ v_in, const float* __restrict__ g_out,
    const float* __restrict__ v_out, const float* __restrict__ b_out,
    double* __restrict__ WTd, float* __restrict__ cb16,
    float* __restrict__ wo16) {
  __shared__ float sv[8 * 1024];
  __shared__ float leafs[64];
  __shared__ float den[8];
  const int tid = threadIdx.x;

  for (int i = tid; i < 8 * 1024; i += 1024) sv[i] = v_in[i];
  __syncthreads();

  // numpy pairwise_sum(1024): 8 leaf blocks of 128 (8-accumulator pattern),
  // combined with the same binary tree as tree8.
  if (tid < 64) {
    const int c = tid >> 3, l = tid & 7;
    const float* a = sv + c * 1024 + l * 128;
    float r[8];
#pragma unroll
    for (int k = 0; k < 8; ++k) r[k] = __fmul_rn(a[k], a[k]);
    for (int i = 8; i < 128; i += 8) {
#pragma unroll
      for (int k = 0; k < 8; ++k)
        r[k] = __fadd_rn(r[k], __fmul_rn(a[i + k], a[i + k]));
    }
    leafs[c * 8 + l] = f_tree8(r);
  }
  __syncthreads();
  if (tid < 8) {
    const float* L = leafs + tid * 8;
    float lr[8];
#pragma unroll
    for (int k = 0; k < 8; ++k) lr[k] = L[k];
    const float s = f_tree8(lr);
    den[tid] = fmaxf(__fsqrt_rn(s), 1e-12f);
  }
  __syncthreads();

  if (tid < 1024) {
    // W_in^T rows (fp32-rounded, widened to f64)
#pragma unroll
    for (int c = 0; c < 8; ++c) {
      const float w = __fdiv_rn(__fmul_rn(g_in[c], sv[c * 1024 + tid]), den[c]);
      WTd[tid * 8 + c] = (double)w;
    }
    // codebook normalize, packed {qn[8], scb, pad[7]}
    {
      const float* cr = cb + tid * 8;
      float q[8];
#pragma unroll
      for (int c = 0; c < 8; ++c) q[c] = cr[c];
      const float nn = f_sumsq8(q);
      const float dd = fmaxf(__fsqrt_rn(nn), 1e-12f);
      float qn[8];
#pragma unroll
      for (int c = 0; c < 8; ++c) {
        qn[c] = __fdiv_rn(q[c], dd);
        cb16[tid * 16 + c] = qn[c];
      }
      cb16[tid * 16 + 8] = f_sumsq8(qn);
#pragma unroll
      for (int c = 9; c < 16; ++c) cb16[tid * 16 + c] = 0.f;
    }
    // W_out weight-norm rows, packed {w[8], b_out, pad[7]}
    {
      const float* vr = v_out + tid * 8;
      float w[8];
#pragma unroll
      for (int c = 0; c < 8; ++c) w[c] = vr[c];
      const float n2 = f_sumsq8(w);
      const float d2 = fmaxf(__fsqrt_rn(n2), 1e-12f);
      const float go = g_out[tid];
#pragma unroll
      for (int c = 0; c < 8; ++c)
        wo16[tid * 16 + c] = __fdiv_rn(__fmul_rn(go, w[c]), d2);
      wo16[tid * 16 + 8] = b_out[tid];
#pragma unroll
      for (int c = 9; c < 16; ++c) wo16[tid * 16 + c] = 0.f;
    }
  }
}

// ---------- main kernel ----------
// Grid: 1024 blocks x 256 threads. Block owns 64 consecutive t of one b.
// Wave q (=tid>>6, forced wave-uniform via readfirstlane) handles the same
// 64 t as the other waves but d/code ranges [q*256, q*256+256).
// All table reads (WTd rows, cb16 rows, wo16 rows) are wave-uniform ->
// scalar/SMEM path, no LDS staging. LDS only for the f64 partial combine
// and the candidate combine (16 KB static).
__global__ __launch_bounds__(256, 4) void vq_main(
    const float* __restrict__ z, const float* __restrict__ cbraw,
    const float* __restrict__ b_in, const double* __restrict__ WTd,
    const float* __restrict__ cb16, const float* __restrict__ wo16,
    float* __restrict__ out, float* __restrict__ oidx,
    float* __restrict__ lossp) {
  __shared__ double accb[2048];  // 16 KB, reused for candidate combine
  const int tid = threadIdx.x;
  const int q0 = __builtin_amdgcn_readfirstlane(tid >> 6);  // wave-uniform
  const int tl = tid & 63;
  const int blk = blockIdx.x;  // 1024 = 16 b * 64 tiles
  const int b = blk >> 6;
  const int tile = blk & 63;
  const int t = tile * 64 + tl;

  // ---- phase 1: partial z_e in f64 over this wave's d-range ----
  const float* zp = z + ((size_t)b * D_ + (size_t)q0 * 256) * T_ + t;
  const double* wd = WTd + (size_t)q0 * 2048;
  double acc[8];
#pragma unroll
  for (int c = 0; c < 8; ++c) acc[c] = 0.0;

#pragma unroll 4
  for (int d = 0; d < 256; ++d) {
    const double zd = (double)zp[(size_t)d * T_];
    const double2* w2 = (const double2*)(wd + d * 8);  // uniform -> s_load
    const double2 w01 = w2[0], w23 = w2[1], w45 = w2[2], w67 = w2[3];
    acc[0] = fma(zd, w01.x, acc[0]);
    acc[1] = fma(zd, w01.y, acc[1]);
    acc[2] = fma(zd, w23.x, acc[2]);
    acc[3] = fma(zd, w23.y, acc[3]);
    acc[4] = fma(zd, w45.x, acc[4]);
    acc[5] = fma(zd, w45.y, acc[5]);
    acc[6] = fma(zd, w67.x, acc[6]);
    acc[7] = fma(zd, w67.y, acc[7]);
  }

  // transposed combine buffer: accb[c][tid] (stride 8B across lanes: free)
#pragma unroll
  for (int c = 0; c < 8; ++c) accb[c * 256 + tid] = acc[c];
  __syncthreads();

  double tot[8];
#pragma unroll
  for (int c = 0; c < 8; ++c) {
    const double* row = accb + c * 256 + tl;
    tot[c] = ((row[0] + row[64]) + row[128]) + row[192];
  }
  __syncthreads();  // accb dead (will be reused)

  // materialize fp32 z_e (+ b_in), normalize (numpy-mimicked)
  float e[8], en[8];
#pragma unroll
  for (int c = 0; c < 8; ++c) e[c] = __fadd_rn((float)tot[c], b_in[c]);
  const float n2 = f_sumsq8(e);
  const float dn = fmaxf(__fsqrt_rn(n2), 1e-12f);
#pragma unroll
  for (int c = 0; c < 8; ++c) en[c] = __fdiv_rn(e[c], dn);
  const float s_enc = f_sumsq8(en);

  // ---- phase 2: nearest code over this wave's code range (scalar rows) ----
  const int j0 = q0 * 256;
  float best = INFINITY;
  int bj = j0;
  {
    const float* cbq = cb16 + (size_t)j0 * 16;
#pragma unroll 4
    for (int jj = 0; jj < 256; ++jj) {
      const float* row = cbq + jj * 16;  // uniform -> s_load
      const float4 lo = *(const float4*)(row);
      const float4 hi = *(const float4*)(row + 4);
      const float sc = row[8];
      float dot = 0.f;
      dot = fmaf(en[0], lo.x, dot);
      dot = fmaf(en[1], lo.y, dot);
      dot = fmaf(en[2], lo.z, dot);
      dot = fmaf(en[3], lo.w, dot);
      dot = fmaf(en[4], hi.x, dot);
      dot = fmaf(en[5], hi.y, dot);
      dot = fmaf(en[6], hi.z, dot);
      dot = fmaf(en[7], hi.w, dot);
      const float dist = __fadd_rn(__fsub_rn(s_enc, __fmul_rn(2.0f, dot)), sc);
      if (dist < best) { best = dist; bj = j0 + jj; }
    }
  }

  // candidate combine (SoA in reused LDS; stride 4B: conflict-free)
  float* distf = (float*)accb;              // 256 f32
  int* candj = (int*)((char*)accb + 1024);  // 256 i32
  distf[tid] = best;
  candj[tid] = bj;
  __syncthreads();

  float bd = distf[tl];
  int bi = candj[tl];
#pragma unroll
  for (int qq = 1; qq < 4; ++qq) {
    const float dd = distf[qq * 64 + tl];
    const int jj = candj[qq * 64 + tl];
    if (dd < bd) { bd = dd; bi = jj; }  // strict <: lower quarter wins ties
  }

  if (tid < 64) oidx[(size_t)b * T_ + t] = (float)bi;

  // raw codebook row for loss + back-projection (divergent 32B gather)
  float cq[8];
  {
    const float* cp = cbraw + (size_t)bi * 8;
#pragma unroll
    for (int c = 0; c < 8; ++c) cq[c] = cp[c];
  }

  // ---- loss partial (wave 0 only; all waves hold identical e, cq) ----
  if (tid < 64) {
    float lsum = 0.f;
#pragma unroll
    for (int c = 0; c < 8; ++c) {
      const float df = __fsub_rn(e[c], cq[c]);
      lsum = fmaf(df, df, lsum);
    }
#pragma unroll
    for (int off = 32; off > 0; off >>= 1)
      lsum += __shfl_down(lsum, off, 64);
    if (tl == 0) lossp[blk] = lsum;
  }

  // ---- phase 3: out[b,d,t] = dot8(cq, W_out_n[d]) + b_out[d] ----
  float* op = out + ((size_t)b * D_ + (size_t)q0 * 256) * T_ + t;
  const float* woq = wo16 + (size_t)q0 * 4096;
#pragma unroll 4
  for (int d = 0; d < 256; ++d) {
    const float* row = woq + d * 16;  // uniform -> s_load
    const float4 lo = *(const float4*)(row);
    const float4 hi = *(const float4*)(row + 4);
    const float bo = row[8];
    float dot = 0.f;
    dot = fmaf(cq[0], lo.x, dot);
    dot = fmaf(cq[1], lo.y, dot);
    dot = fmaf(cq[2], lo.z, dot);
    dot = fmaf(cq[3], lo.w, dot);
    dot = fmaf(cq[4], hi.x, dot);
    dot = fmaf(cq[5], hi.y, dot);
    dot = fmaf(cq[6], hi.z, dot);
    dot = fmaf(cq[7], hi.w, dot);
    op[(size_t)d * T_] = __fadd_rn(dot, bo);
  }
}

// ---------- finalize loss ----------
__global__ __launch_bounds__(64) void vq_fin(const float* __restrict__ lossp,
                                             float* __restrict__ oloss) {
  const int tid = threadIdx.x;
  if (tid < B_) {
    float s = 0.f;
    for (int i = 0; i < 64; ++i) s += lossp[tid * 64 + i];
    oloss[tid] = s * (1.25f / 32768.0f);
  }
}

extern "C" void kernel_launch(void* const* d_in, const int* in_sizes, int n_in,
                              void* d_out, int out_size, void* d_ws,
                              size_t ws_size, hipStream_t stream) {
  (void)in_sizes; (void)n_in; (void)out_size; (void)ws_size;
  const float* z = (const float*)d_in[0];
  const float* cb = (const float*)d_in[1];
  const float* g_in = (const float*)d_in[2];
  const float* v_in = (const float*)d_in[3];
  const float* b_in = (const float*)d_in[4];
  const float* g_out = (const float*)d_in[5];
  const float* v_out = (const float*)d_in[6];
  const float* b_out = (const float*)d_in[7];
  float* out = (float*)d_out;

  char* ws = (char*)d_ws;
  double* WTd = (double*)ws;              // 65536 B
  float* cb16 = (float*)(ws + 65536);     // 65536 B
  float* wo16 = (float*)(ws + 131072);    // 65536 B
  float* lossp = (float*)(ws + 196608);   // 4096 B

  float* oidx = out + (size_t)B_ * D_ * T_;
  float* oloss = oidx + (size_t)B_ * T_;

  vq_setup<<<1, 1024, 0, stream>>>(cb, g_in, v_in, g_out, v_out, b_out, WTd,
                                   cb16, wo16);
  vq_main<<<1024, 256, 0, stream>>>(z, cb, b_in, WTd, cb16, wo16, out, oidx,
                                    lossp);
  vq_fin<<<1, 64, 0, stream>>>(lossp, oloss);
}

// Round 4
// 186.539 us; speedup vs baseline: 1.5568x; 1.0089x over previous
//
#include <hip/hip_runtime.h>
#include <math.h>

#define B_ 16
#define D_ 1024
#define T_ 4096
#define CS_ 1024
#define CD_ 8

// ---------- numpy-mimicking fp32 helpers ----------
__device__ __forceinline__ float f_tree8(const float r[8]) {
  return __fadd_rn(
      __fadd_rn(__fadd_rn(r[0], r[1]), __fadd_rn(r[2], r[3])),
      __fadd_rn(__fadd_rn(r[4], r[5]), __fadd_rn(r[6], r[7])));
}
__device__ __forceinline__ float f_sumsq8(const float x[8]) {
  float s[8];
#pragma unroll
  for (int k = 0; k < 8; ++k) s[k] = __fmul_rn(x[k], x[k]);
  return f_tree8(s);
}

// ---------- setup: normalize W_in, W_out, codebook; pack tables ----------
// ws layout:
//   WTd  : double[1024][8]   (W_in^T, fp32-rounded widened to f64)  @ 0      (65536 B)
//   cb16 : float [1024][16]  ({cbn[8], scb, pad})                   @ 65536  (65536 B)
//   wo16 : float [1024][16]  ({woutn[8], b_out, pad})               @ 131072 (65536 B)
//   lossp: float [1024]                                             @ 196608 (4096 B)
__global__ __launch_bounds__(1024) void vq_setup(
    const float* __restrict__ cb, const float* __restrict__ g_in,
    const float* __restrict__ v_in, const float* __restrict__ g_out,
    const float* __restrict__ v_out, const float* __restrict__ b_out,
    double* __restrict__ WTd, float* __restrict__ cb16,
    float* __restrict__ wo16) {
  __shared__ float sv[8 * 1024];
  __shared__ float leafs[64];
  __shared__ float den[8];
  const int tid = threadIdx.x;

  for (int i = tid; i < 8 * 1024; i += 1024) sv[i] = v_in[i];
  __syncthreads();

  // numpy pairwise_sum(1024): 8 leaf blocks of 128 (8-accumulator pattern),
  // combined with the same binary tree as tree8.
  if (tid < 64) {
    const int c = tid >> 3, l = tid & 7;
    const float* a = sv + c * 1024 + l * 128;
    float r[8];
#pragma unroll
    for (int k = 0; k < 8; ++k) r[k] = __fmul_rn(a[k], a[k]);
    for (int i = 8; i < 128; i += 8) {
#pragma unroll
      for (int k = 0; k < 8; ++k)
        r[k] = __fadd_rn(r[k], __fmul_rn(a[i + k], a[i + k]));
    }
    leafs[c * 8 + l] = f_tree8(r);
  }
  __syncthreads();
  if (tid < 8) {
    const float* L = leafs + tid * 8;
    float lr[8];
#pragma unroll
    for (int k = 0; k < 8; ++k) lr[k] = L[k];
    const float s = f_tree8(lr);
    den[tid] = fmaxf(__fsqrt_rn(s), 1e-12f);
  }
  __syncthreads();

  if (tid < 1024) {
#pragma unroll
    for (int c = 0; c < 8; ++c) {
      const float w = __fdiv_rn(__fmul_rn(g_in[c], sv[c * 1024 + tid]), den[c]);
      WTd[tid * 8 + c] = (double)w;
    }
    {
      const float* cr = cb + tid * 8;
      float q[8];
#pragma unroll
      for (int c = 0; c < 8; ++c) q[c] = cr[c];
      const float nn = f_sumsq8(q);
      const float dd = fmaxf(__fsqrt_rn(nn), 1e-12f);
      float qn[8];
#pragma unroll
      for (int c = 0; c < 8; ++c) {
        qn[c] = __fdiv_rn(q[c], dd);
        cb16[tid * 16 + c] = qn[c];
      }
      cb16[tid * 16 + 8] = f_sumsq8(qn);
#pragma unroll
      for (int c = 9; c < 16; ++c) cb16[tid * 16 + c] = 0.f;
    }
    {
      const float* vr = v_out + tid * 8;
      float w[8];
#pragma unroll
      for (int c = 0; c < 8; ++c) w[c] = vr[c];
      const float n2 = f_sumsq8(w);
      const float d2 = fmaxf(__fsqrt_rn(n2), 1e-12f);
      const float go = g_out[tid];
#pragma unroll
      for (int c = 0; c < 8; ++c)
        wo16[tid * 16 + c] = __fdiv_rn(__fmul_rn(go, w[c]), d2);
      wo16[tid * 16 + 8] = b_out[tid];
#pragma unroll
      for (int c = 9; c < 16; ++c) wo16[tid * 16 + c] = 0.f;
    }
  }
}

// ---------- main kernel ----------
// Grid: 1024 blocks x 512 threads (8 waves). Block owns 64 consecutive t of
// one b. Wave q (=tid>>6, wave-uniform) handles the same 64 t as the other
// waves but d/code OCTANT [q*128, q*128+128).
// All table reads are wave-uniform -> scalar/SMEM path. LDS only for the
// f64 partial combine + candidate combine (32 KB static).
// 1024 blocks / 256 CU = 4 blocks/CU x 8 waves = 32 waves/CU (100% occ).
__global__ __launch_bounds__(512, 8) void vq_main(
    const float* __restrict__ z, const float* __restrict__ cbraw,
    const float* __restrict__ b_in, const double* __restrict__ WTd,
    const float* __restrict__ cb16, const float* __restrict__ wo16,
    float* __restrict__ out, float* __restrict__ oidx,
    float* __restrict__ lossp) {
  __shared__ double accb[4096];  // 32 KB, reused for candidate combine
  const int tid = threadIdx.x;
  const int q0 = __builtin_amdgcn_readfirstlane(tid >> 6);  // wave id 0..7
  const int tl = tid & 63;
  const int blk = blockIdx.x;  // 1024 = 16 b * 64 tiles
  const int b = blk >> 6;
  const int tile = blk & 63;
  const int t = tile * 64 + tl;

  // ---- phase 1: partial z_e in f64 over this wave's 128-d octant ----
  const float* zp = z + ((size_t)b * D_ + (size_t)q0 * 128) * T_ + t;
  const double* wd = WTd + (size_t)q0 * 1024;
  double acc[8];
#pragma unroll
  for (int c = 0; c < 8; ++c) acc[c] = 0.0;

#pragma unroll 8
  for (int d = 0; d < 128; ++d) {
    const double zd = (double)zp[(size_t)d * T_];
    const double2* w2 = (const double2*)(wd + d * 8);  // uniform -> s_load
    const double2 w01 = w2[0], w23 = w2[1], w45 = w2[2], w67 = w2[3];
    acc[0] = fma(zd, w01.x, acc[0]);
    acc[1] = fma(zd, w01.y, acc[1]);
    acc[2] = fma(zd, w23.x, acc[2]);
    acc[3] = fma(zd, w23.y, acc[3]);
    acc[4] = fma(zd, w45.x, acc[4]);
    acc[5] = fma(zd, w45.y, acc[5]);
    acc[6] = fma(zd, w67.x, acc[6]);
    acc[7] = fma(zd, w67.y, acc[7]);
  }

  // transposed combine buffer: accb[c][tid] (stride 8B across lanes: free)
#pragma unroll
  for (int c = 0; c < 8; ++c) accb[c * 512 + tid] = acc[c];
  __syncthreads();

  double tot[8];
#pragma unroll
  for (int c = 0; c < 8; ++c) {
    const double* row = accb + c * 512 + tl;
    double s = row[0];
#pragma unroll
    for (int qq = 1; qq < 8; ++qq) s = s + row[qq * 64];
    tot[c] = s;
  }
  __syncthreads();  // accb dead (will be reused)

  // materialize fp32 z_e (+ b_in), normalize (numpy-mimicked)
  float e[8], en[8];
#pragma unroll
  for (int c = 0; c < 8; ++c) e[c] = __fadd_rn((float)tot[c], b_in[c]);
  const float n2 = f_sumsq8(e);
  const float dn = fmaxf(__fsqrt_rn(n2), 1e-12f);
#pragma unroll
  for (int c = 0; c < 8; ++c) en[c] = __fdiv_rn(e[c], dn);
  const float s_enc = f_sumsq8(en);

  // ---- phase 2: nearest code over this wave's 128-code octant ----
  const int j0 = q0 * 128;
  float best = INFINITY;
  int bj = j0;
  {
    const float* cbq = cb16 + (size_t)j0 * 16;
#pragma unroll 4
    for (int jj = 0; jj < 128; ++jj) {
      const float* row = cbq + jj * 16;  // uniform -> s_load
      const float4 lo = *(const float4*)(row);
      const float4 hi = *(const float4*)(row + 4);
      const float sc = row[8];
      float dot = 0.f;
      dot = fmaf(en[0], lo.x, dot);
      dot = fmaf(en[1], lo.y, dot);
      dot = fmaf(en[2], lo.z, dot);
      dot = fmaf(en[3], lo.w, dot);
      dot = fmaf(en[4], hi.x, dot);
      dot = fmaf(en[5], hi.y, dot);
      dot = fmaf(en[6], hi.z, dot);
      dot = fmaf(en[7], hi.w, dot);
      const float dist = __fadd_rn(__fsub_rn(s_enc, __fmul_rn(2.0f, dot)), sc);
      if (dist < best) { best = dist; bj = j0 + jj; }
    }
  }

  // candidate combine (SoA in reused LDS; stride 4B: conflict-free)
  float* distf = (float*)accb;              // 512 f32
  int* candj = (int*)((char*)accb + 2048);  // 512 i32
  distf[tid] = best;
  candj[tid] = bj;
  __syncthreads();

  float bd = distf[tl];
  int bi = candj[tl];
#pragma unroll
  for (int qq = 1; qq < 8; ++qq) {
    const float dd = distf[qq * 64 + tl];
    const int jj = candj[qq * 64 + tl];
    if (dd < bd) { bd = dd; bi = jj; }  // strict <: lower octant wins ties
  }

  if (tid < 64) oidx[(size_t)b * T_ + t] = (float)bi;

  // raw codebook row for loss + back-projection (divergent 32B gather)
  float cq[8];
  {
    const float* cp = cbraw + (size_t)bi * 8;
#pragma unroll
    for (int c = 0; c < 8; ++c) cq[c] = cp[c];
  }

  // ---- loss partial (wave 0 only; all waves hold identical e, cq) ----
  if (tid < 64) {
    float lsum = 0.f;
#pragma unroll
    for (int c = 0; c < 8; ++c) {
      const float df = __fsub_rn(e[c], cq[c]);
      lsum = fmaf(df, df, lsum);
    }
#pragma unroll
    for (int off = 32; off > 0; off >>= 1)
      lsum += __shfl_down(lsum, off, 64);
    if (tl == 0) lossp[blk] = lsum;
  }

  // ---- phase 3: out[b,d,t] = dot8(cq, W_out_n[d]) + b_out[d] ----
  float* op = out + ((size_t)b * D_ + (size_t)q0 * 128) * T_ + t;
  const float* woq = wo16 + (size_t)q0 * 2048;
#pragma unroll 4
  for (int d = 0; d < 128; ++d) {
    const float* row = woq + d * 16;  // uniform -> s_load
    const float4 lo = *(const float4*)(row);
    const float4 hi = *(const float4*)(row + 4);
    const float bo = row[8];
    float dot = 0.f;
    dot = fmaf(cq[0], lo.x, dot);
    dot = fmaf(cq[1], lo.y, dot);
    dot = fmaf(cq[2], lo.z, dot);
    dot = fmaf(cq[3], lo.w, dot);
    dot = fmaf(cq[4], hi.x, dot);
    dot = fmaf(cq[5], hi.y, dot);
    dot = fmaf(cq[6], hi.z, dot);
    dot = fmaf(cq[7], hi.w, dot);
    op[(size_t)d * T_] = __fadd_rn(dot, bo);
  }
}

// ---------- finalize loss ----------
__global__ __launch_bounds__(64) void vq_fin(const float* __restrict__ lossp,
                                             float* __restrict__ oloss) {
  const int tid = threadIdx.x;
  if (tid < B_) {
    float s = 0.f;
    for (int i = 0; i < 64; ++i) s += lossp[tid * 64 + i];
    oloss[tid] = s * (1.25f / 32768.0f);
  }
}

extern "C" void kernel_launch(void* const* d_in, const int* in_sizes, int n_in,
                              void* d_out, int out_size, void* d_ws,
                              size_t ws_size, hipStream_t stream) {
  (void)in_sizes; (void)n_in; (void)out_size; (void)ws_size;
  const float* z = (const float*)d_in[0];
  const float* cb = (const float*)d_in[1];
  const float* g_in = (const float*)d_in[2];
  const float* v_in = (const float*)d_in[3];
  const float* b_in = (const float*)d_in[4];
  const float* g_out = (const float*)d_in[5];
  const float* v_out = (const float*)d_in[6];
  const float* b_out = (const float*)d_in[7];
  float* out = (float*)d_out;

  char* ws = (char*)d_ws;
  double* WTd = (double*)ws;              // 65536 B
  float* cb16 = (float*)(ws + 65536);     // 65536 B
  float* wo16 = (float*)(ws + 131072);    // 65536 B
  float* lossp = (float*)(ws + 196608);   // 4096 B

  float* oidx = out + (size_t)B_ * D_ * T_;
  float* oloss = oidx + (size_t)B_ * T_;

  vq_setup<<<1, 1024, 0, stream>>>(cb, g_in, v_in, g_out, v_out, b_out, WTd,
                                   cb16, wo16);
  vq_main<<<1024, 512, 0, stream>>>(z, cb, b_in, WTd, cb16, wo16, out, oidx,
                                    lossp);
  vq_fin<<<1, 64, 0, stream>>>(lossp, oloss);
}